// Round 1
// 402.638 us; speedup vs baseline: 3.0369x; 3.0369x over previous
//
#include <hip/hip_runtime.h>
#include <hip/hip_bf16.h>

typedef __attribute__((ext_vector_type(8))) short s16x8;
typedef __attribute__((ext_vector_type(4))) float f32x4;
typedef unsigned short u16;

// ---------------- workspace layout (bytes), total <= 41,943,040 (proven) ----------------
#define WS_FWD    0            // 384 int
#define WS_SCALE  4096         // 384 f32
#define WS_OFFS   6144         // 384 f32
#define WS_WHI    8192         // packed w_hi bf16: 4*6*384*32*2 = 589,824 B -> ends 598,016
#define WS_XD     2097152      // xd (b,h,w,192) bf16 = 12,582,912 B; later reused as y2'
#define WS_WLO    14680064     // packed w_lo bf16: 9*6*384*32*2 = 1,327,104 B -> ends 16,007,168
#define WS_A      16777216     // a1/a2 bf16 (pix,384) = 25,165,824 B -> ends 41,943,040

static __device__ __forceinline__ u16 f2bf(float f) {
    __hip_bfloat16 h = __float2bfloat16(f);
    return *reinterpret_cast<u16*>(&h);
}
static __device__ __forceinline__ float bf2f(u16 u) {
    __hip_bfloat16 h = *reinterpret_cast<__hip_bfloat16*>(&u);
    return __bfloat162float(h);
}

// ---------------- prep: perm index + scale/offset (R9-proven) ----------------
__global__ __launch_bounds__(256)
void k_prep0(const float* __restrict__ pw, const float* __restrict__ an,
             const float* __restrict__ ao, int* __restrict__ fwd,
             float* __restrict__ scale, float* __restrict__ offs)
{
    int o = blockIdx.x * 256 + threadIdx.x;
    if (o >= 384) return;
    int f = 0;
    for (int c = 0; c < 384; ++c)
        if (pw[(size_t)o * 384 + c] > 0.5f) f = c;
    fwd[o]   = f;
    scale[o] = 0.2f * log1pf(expf(0.5f * an[o]));
    offs[o]  = ao[o];
}

// ---------------- pack w_hi into bf16 MFMA B-fragment layout ----------------
// out[((t*6 + kc)*384 + n)*32 + c32], c = kc*32 + c32 in down-domain channel order.
// Tap masking (down-domain formula) moved here from the hot loop.
__global__ __launch_bounds__(256)
void k_pack_hi(const float* __restrict__ w, u16* __restrict__ wp)
{
    int gid = blockIdx.x * 256 + threadIdx.x;   // 294,912 exact (1152 blocks)
    int c32 = gid & 31;
    int n   = (gid >> 5) % 384;
    int tkc = gid / (384 * 32);
    int kc  = tkc % 6;
    int t   = tkc / 6;
    int c   = kc * 32 + c32;
    int th = t >> 1, tw = t & 1;
    int cin = c >> 2, dy = (c >> 1) & 1, dx = c & 1;
    float wv = 0.f;
    if (!(th == 0 && dy == 0) && !(tw == 0 && dx == 0)) {
        int ky = (th == 0) ? 0 : 1 + dy;
        int kx = (tw == 0) ? 0 : 1 + dx;
        wv = w[(((size_t)n * 48 + cin) * 3 + ky) * 3 + kx];
    }
    wp[gid] = f2bf(wv);
}

// ---------------- pack w_lo into bf16 MFMA B-fragment layout ----------------
__global__ __launch_bounds__(256)
void k_pack_lo(const float* __restrict__ w, u16* __restrict__ wp)
{
    int gid = blockIdx.x * 256 + threadIdx.x;   // 663,552 exact (2592 blocks)
    int c32 = gid & 31;
    int n   = (gid >> 5) % 384;
    int tkc = gid / (384 * 32);
    int kc  = tkc % 6;
    int t   = tkc / 6;
    int c   = kc * 32 + c32;
    wp[gid] = f2bf(w[((size_t)n * 192 + c) * 9 + t]);
}

// ---------------- X1d: down(x1) to (b,h,w,192) bf16 ----------------
__global__ __launch_bounds__(256)
void k_xd(const float* __restrict__ x, u16* __restrict__ xd)
{
    int gid = blockIdx.x * 256 + threadIdx.x;   // 6,291,456 exact
    int pix = gid / 192;
    int c = gid - pix * 192;                    // c = cin*4 + dy*2 + dx
    int b = pix >> 10, h = (pix >> 5) & 31, w = pix & 31;
    xd[gid] = f2bf(x[(((size_t)b * 96 + (c >> 2)) * 64 + (2 * h + ((c >> 1) & 1))) * 64
                     + (2 * w + (c & 1))]);
}

// ---------------- MFMA gemm with pre-packed bf16 weights ----------------
// A: global vector loads from in_t (.,192) bf16; B: coalesced vector loads from
// packed bf16 weights (1 KiB/wave/instruction, L2/LLC-resident).
// Tile: M=64 (rows h0,h0+1), N=384 wave-split (96/wave). Same epilogue beliefs as R10.
template <int T>
__global__ __launch_bounds__(256)
void s_gemm(const u16* __restrict__ in_t, const u16* __restrict__ wpk,
            const float* __restrict__ bias, u16* __restrict__ out_a)
{
    const int tid = threadIdx.x;
    const int lane = tid & 63;
    const int wave = tid >> 6;
    const int l16 = lane & 15;
    const int quad = lane >> 4;
    const int mblk = blockIdx.x;           // 512 blocks
    const int b = mblk >> 4;
    const int h0 = (mblk & 15) << 1;
    const int n0 = wave * 96;

    const f32x4 zero4 = {0.f, 0.f, 0.f, 0.f};
    f32x4 acc[4][6];
#pragma unroll
    for (int a = 0; a < 4; ++a)
#pragma unroll
        for (int c = 0; c < 6; ++c) acc[a][c] = zero4;

    for (int t = 0; t < T; ++t) {
        const int dh = (T == 4) ? ((t >> 1) - 1) : (t / 3 - 1);
        const int dw = (T == 4) ? ((t & 1) - 1) : (t % 3 - 1);
        for (int kc = 0; kc < 6; ++kc) {
            // ---- B fragments: coalesced vector loads from packed weights ----
            const u16* wp = wpk + ((size_t)(t * 6 + kc) * 384) * 32;
            s16x8 bf[6];
#pragma unroll
            for (int ns = 0; ns < 6; ++ns)
                bf[ns] = *(const s16x8*)(wp + (n0 + ns * 16 + l16) * 32 + quad * 8);
            // ---- A fragments: direct global vector loads, per-lane bounds check ----
            s16x8 af[4];
#pragma unroll
            for (int ms = 0; ms < 4; ++ms) {
                int m = ms * 16 + l16;
                int ih = h0 + (m >> 5) + dh;
                int iw = (m & 31) + dw;
                s16x8 v = {0, 0, 0, 0, 0, 0, 0, 0};
                if (ih >= 0 && ih < 32 && iw >= 0 && iw < 32)
                    v = *(const s16x8*)(in_t + (((size_t)b * 32 + ih) * 32 + iw) * 192
                                        + kc * 32 + quad * 8);
                af[ms] = v;
            }
            // ---- MFMA ----
#pragma unroll
            for (int ms = 0; ms < 4; ++ms)
#pragma unroll
                for (int ns = 0; ns < 6; ++ns)
                    acc[ms][ns] = __builtin_amdgcn_mfma_f32_16x16x32_bf16(
                        af[ms], bf[ns], acc[ms][ns], 0, 0, 0);
        }
    }

    // epilogue: C/D belief col(N)=lane&15, row(M)=quad*4+reg
#pragma unroll
    for (int ms = 0; ms < 4; ++ms) {
#pragma unroll
        for (int ns = 0; ns < 6; ++ns) {
            int n = n0 + ns * 16 + l16;
            float bv = bias[n];
#pragma unroll
            for (int r4 = 0; r4 < 4; ++r4) {
                int m = ms * 16 + quad * 4 + r4;
                int h = h0 + (m >> 5);
                int w = m & 31;
                out_a[(((size_t)b * 32 + h) * 32 + w) * 384 + n] =
                    f2bf(acc[ms][ns][r4] + bv);
            }
        }
    }
}

// ---------------- naive e1 (R9-proven) ----------------
__global__ __launch_bounds__(256)
void n_e1(const u16* __restrict__ a, const float* __restrict__ x,
          u16* __restrict__ y2)
{
    int gid = blockIdx.x * 256 + threadIdx.x;        // 6,291,456 exact
    int c = gid % 192;
    int pix = gid / 192;
    int b = pix >> 10, h = (pix >> 5) & 31, w = pix & 31;
    float a_s = bf2f(a[(size_t)pix * 384 + c]);
    float a_o = bf2f(a[(size_t)pix * 384 + 192 + c]);
    float xv = x[(((size_t)b * 96 + 48 + (c >> 2)) * 64 + (2 * h + ((c >> 1) & 1))) * 64
                 + (2 * w + (c & 1))];
    float e = expf(0.4f * a_s);
    float sj = 2.f - 4.f / (e + 1.f);
    y2[gid] = f2bf(xv * expf(sj) + a_o);
}

// ---------------- naive out y2-half (R9-proven) ----------------
__global__ __launch_bounds__(256)
void n_o2(const u16* __restrict__ y2, const float* __restrict__ scale,
          const float* __restrict__ offs, const int* __restrict__ fwd,
          float* __restrict__ out)
{
    int gid = blockIdx.x * 256 + threadIdx.x;        // 12,582,912 exact
    int w = gid & 31;
    int h = (gid >> 5) & 31;
    int t = gid >> 10;
    int o = t % 384;
    int b = t / 384;
    int c = fwd[o];
    if (c >= 192) {
        float z = bf2f(y2[(((size_t)b * 32 + h) * 32 + w) * 192 + (c - 192)]);
        out[gid] = z * scale[c] + offs[c];
    }
}

// ---------------- naive out y1-half (R9-proven) ----------------
__global__ __launch_bounds__(256)
void n_o1(const float* __restrict__ x, const u16* __restrict__ a,
          const float* __restrict__ scale, const float* __restrict__ offs,
          const int* __restrict__ fwd, float* __restrict__ out)
{
    int gid = blockIdx.x * 256 + threadIdx.x;        // 12,582,912 exact
    int w = gid & 31;
    int h = (gid >> 5) & 31;
    int t = gid >> 10;
    int o = t % 384;
    int b = t / 384;
    int c = fwd[o];
    if (c < 192) {
        size_t pix = ((size_t)b * 32 + h) * 32 + w;
        float a_s = bf2f(a[pix * 384 + c]);
        float a_o = bf2f(a[pix * 384 + 192 + c]);
        float xv = x[(((size_t)b * 96 + (c >> 2)) * 64 + (2 * h + ((c >> 1) & 1))) * 64
                     + (2 * w + (c & 1))];
        float e = expf(0.4f * a_s);
        float sj = 2.f - 4.f / (e + 1.f);
        float z = xv * expf(sj) + a_o;
        out[gid] = z * scale[c] + offs[c];
    }
}

extern "C" void kernel_launch(void* const* d_in, const int* in_sizes, int n_in,
                              void* d_out, int out_size, void* d_ws, size_t ws_size,
                              hipStream_t stream)
{
    const float* x        = (const float*)d_in[0];
    const float* w_hi     = (const float*)d_in[1];
    const float* b_hi     = (const float*)d_in[2];
    const float* w_lo     = (const float*)d_in[3];
    const float* b_lo     = (const float*)d_in[4];
    const float* act_norm = (const float*)d_in[5];
    const float* act_off  = (const float*)d_in[6];
    const float* perm_w   = (const float*)d_in[7];
    float* out = (float*)d_out;
    char* ws = (char*)d_ws;

    int*   fwd   = (int*)(ws + WS_FWD);
    float* scale = (float*)(ws + WS_SCALE);
    float* offs  = (float*)(ws + WS_OFFS);
    u16*   whi   = (u16*)(ws + WS_WHI);  // packed w_hi bf16 fragments
    u16*   xd    = (u16*)(ws + WS_XD);   // xd, then reused as y2'
    u16*   wlo   = (u16*)(ws + WS_WLO);  // packed w_lo bf16 fragments
    u16*   abuf  = (u16*)(ws + WS_A);    // a1, then a2

    k_prep0<<<2, 256, 0, stream>>>(perm_w, act_norm, act_off, fwd, scale, offs);
    k_pack_hi<<<1152, 256, 0, stream>>>(w_hi, whi);
    k_pack_lo<<<2592, 256, 0, stream>>>(w_lo, wlo);
    k_xd<<<24576, 256, 0, stream>>>(x, xd);
    s_gemm<4><<<512, 256, 0, stream>>>(xd, whi, b_hi, abuf);         // a1 (packed-B MFMA)
    n_e1<<<24576, 256, 0, stream>>>(abuf, x, xd);                    // y2' (over xd)
    n_o2<<<49152, 256, 0, stream>>>(xd, scale, offs, fwd, out);      // y2 half of out
    s_gemm<9><<<512, 256, 0, stream>>>(xd, wlo, b_lo, abuf);         // a2 (packed-B MFMA)
    n_o1<<<49152, 256, 0, stream>>>(x, abuf, scale, offs, fwd, out); // y1 half of out
}

// Round 2
// 321.451 us; speedup vs baseline: 3.8040x; 1.2526x over previous
//
#include <hip/hip_runtime.h>
#include <hip/hip_bf16.h>

typedef __attribute__((ext_vector_type(8))) short s16x8;
typedef __attribute__((ext_vector_type(4))) float f32x4;
typedef unsigned short u16;

// ---------------- workspace layout (bytes), total <= 41,943,040 (proven) ----------------
#define WS_FWD    0            // 384 int
#define WS_INV    2048         // 384 int (inverse perm: inv[c] = o)
#define WS_SCALE  4096         // 384 f32
#define WS_OFFS   6144         // 384 f32
#define WS_WHI    8192         // packed w_hi bf16: 4*6*384*32*2 = 589,824 B -> ends 598,016
#define WS_XD     2097152      // xd = down(x1) (b,h,w,192) bf16 = 12,582,912 B (NOT overwritten)
#define WS_WLO    14680064     // packed w_lo bf16: 9*6*384*32*2 = 1,327,104 B -> ends 16,007,168
#define WS_Y2     16777216     // y2' (b,h,w,192) bf16 = 12,582,912 B -> ends 29,360,128

static __device__ __forceinline__ u16 f2bf(float f) {
    __hip_bfloat16 h = __float2bfloat16(f);
    return *reinterpret_cast<u16*>(&h);
}
static __device__ __forceinline__ float bf2f(u16 u) {
    __hip_bfloat16 h = *reinterpret_cast<__hip_bfloat16*>(&u);
    return __bfloat162float(h);
}

// ---------------- prep: perm index (fwd + inv) + scale/offset ----------------
__global__ __launch_bounds__(256)
void k_prep0(const float* __restrict__ pw, const float* __restrict__ an,
             const float* __restrict__ ao, int* __restrict__ fwd,
             int* __restrict__ inv, float* __restrict__ scale,
             float* __restrict__ offs)
{
    int o = blockIdx.x * 256 + threadIdx.x;
    if (o >= 384) return;
    int f = 0;
    for (int c = 0; c < 384; ++c)
        if (pw[(size_t)o * 384 + c] > 0.5f) f = c;
    fwd[o]   = f;
    inv[f]   = o;
    scale[o] = 0.2f * log1pf(expf(0.5f * an[o]));
    offs[o]  = ao[o];
}

// ---------------- pack w_hi into bf16 MFMA B-fragment layout ----------------
__global__ __launch_bounds__(256)
void k_pack_hi(const float* __restrict__ w, u16* __restrict__ wp)
{
    int gid = blockIdx.x * 256 + threadIdx.x;   // 294,912 exact (1152 blocks)
    int c32 = gid & 31;
    int n   = (gid >> 5) % 384;
    int tkc = gid / (384 * 32);
    int kc  = tkc % 6;
    int t   = tkc / 6;
    int c   = kc * 32 + c32;
    int th = t >> 1, tw = t & 1;
    int cin = c >> 2, dy = (c >> 1) & 1, dx = c & 1;
    float wv = 0.f;
    if (!(th == 0 && dy == 0) && !(tw == 0 && dx == 0)) {
        int ky = (th == 0) ? 0 : 1 + dy;
        int kx = (tw == 0) ? 0 : 1 + dx;
        wv = w[(((size_t)n * 48 + cin) * 3 + ky) * 3 + kx];
    }
    wp[gid] = f2bf(wv);
}

// ---------------- pack w_lo into bf16 MFMA B-fragment layout ----------------
__global__ __launch_bounds__(256)
void k_pack_lo(const float* __restrict__ w, u16* __restrict__ wp)
{
    int gid = blockIdx.x * 256 + threadIdx.x;   // 663,552 exact (2592 blocks)
    int c32 = gid & 31;
    int n   = (gid >> 5) % 384;
    int tkc = gid / (384 * 32);
    int kc  = tkc % 6;
    int t   = tkc / 6;
    int c   = kc * 32 + c32;
    wp[gid] = f2bf(w[((size_t)n * 192 + c) * 9 + t]);
}

// ---------------- X1d: down(x1) to (b,h,w,192) bf16 ----------------
__global__ __launch_bounds__(256)
void k_xd(const float* __restrict__ x, u16* __restrict__ xd)
{
    int gid = blockIdx.x * 256 + threadIdx.x;   // 6,291,456 exact
    int pix = gid / 192;
    int c = gid - pix * 192;                    // c = cin*4 + dy*2 + dx
    int b = pix >> 10, h = (pix >> 5) & 31, w = pix & 31;
    xd[gid] = f2bf(x[(((size_t)b * 96 + (c >> 2)) * 64 + (2 * h + ((c >> 1) & 1))) * 64
                     + (2 * w + (c & 1))]);
}

// ---------------- fused MFMA gemm + affine + permuted-output epilogue ----------------
// T=4: conv_hi over xd; epilogue computes y2' = x2d*exp(sj)+a_o (e1) -> writes y2'
//      AND the y2-half of out (old n_o2).
// T=9: conv_lo over y2'; epilogue computes y1 out-half (old n_o1).
// a (=acc+bias, bf16) staged in LDS [64][392-padded] so every thread sees all 384 ch.
template <int T>
__global__ __launch_bounds__(256)
void f_gemm(const u16* __restrict__ in_t, const u16* __restrict__ wpk,
            const float* __restrict__ bias, const float* __restrict__ x,
            const int* __restrict__ inv, const float* __restrict__ scale,
            const float* __restrict__ offs, u16* __restrict__ y2out,
            float* __restrict__ out)
{
    const int tid = threadIdx.x;
    const int lane = tid & 63;
    const int wave = tid >> 6;
    const int l16 = lane & 15;
    const int quad = lane >> 4;
    const int mblk = blockIdx.x;           // 512 blocks
    const int b = mblk >> 4;
    const int h0 = (mblk & 15) << 1;
    const int n0 = wave * 96;

    __shared__ u16 a_lds[64 * 392];        // 50,176 B; row stride 392 u16 (16B-aligned rows)

    const f32x4 zero4 = {0.f, 0.f, 0.f, 0.f};
    f32x4 acc[4][6];
#pragma unroll
    for (int a = 0; a < 4; ++a)
#pragma unroll
        for (int c = 0; c < 6; ++c) acc[a][c] = zero4;

    for (int t = 0; t < T; ++t) {
        const int dh = (T == 4) ? ((t >> 1) - 1) : (t / 3 - 1);
        const int dw = (T == 4) ? ((t & 1) - 1) : (t % 3 - 1);
        for (int kc = 0; kc < 6; ++kc) {
            // ---- B fragments: coalesced vector loads from packed weights ----
            const u16* wp = wpk + ((size_t)(t * 6 + kc) * 384) * 32;
            s16x8 bf[6];
#pragma unroll
            for (int ns = 0; ns < 6; ++ns)
                bf[ns] = *(const s16x8*)(wp + (n0 + ns * 16 + l16) * 32 + quad * 8);
            // ---- A fragments: direct global vector loads, per-lane bounds check ----
            s16x8 af[4];
#pragma unroll
            for (int ms = 0; ms < 4; ++ms) {
                int m = ms * 16 + l16;
                int ih = h0 + (m >> 5) + dh;
                int iw = (m & 31) + dw;
                s16x8 v = {0, 0, 0, 0, 0, 0, 0, 0};
                if (ih >= 0 && ih < 32 && iw >= 0 && iw < 32)
                    v = *(const s16x8*)(in_t + (((size_t)b * 32 + ih) * 32 + iw) * 192
                                        + kc * 32 + quad * 8);
                af[ms] = v;
            }
            // ---- MFMA ----
#pragma unroll
            for (int ms = 0; ms < 4; ++ms)
#pragma unroll
                for (int ns = 0; ns < 6; ++ns)
                    acc[ms][ns] = __builtin_amdgcn_mfma_f32_16x16x32_bf16(
                        af[ms], bf[ns], acc[ms][ns], 0, 0, 0);
        }
    }

    // ---- epilogue phase 1: a = f2bf(acc + bias) into LDS ----
    // C/D belief: col(N)=lane&15, row(M)=quad*4+reg
#pragma unroll
    for (int ms = 0; ms < 4; ++ms) {
#pragma unroll
        for (int ns = 0; ns < 6; ++ns) {
            int n = n0 + ns * 16 + l16;
            float bv = bias[n];
#pragma unroll
            for (int r4 = 0; r4 < 4; ++r4) {
                int m = ms * 16 + quad * 4 + r4;
                a_lds[m * 392 + n] = f2bf(acc[ms][ns][r4] + bv);
            }
        }
    }
    __syncthreads();

    // ---- epilogue phase 2: affine + permuted output (64 m x 192 c, 8 c per thread) ----
    for (int it = 0; it < 6; ++it) {
        int v = it * 256 + tid;            // 0..1535
        int m = v / 24;
        int c8 = v - m * 24;
        int c0 = c8 * 8;
        int h = h0 + (m >> 5);
        int w = m & 31;
        size_t pix = ((size_t)b * 32 + h) * 32 + w;

        s16x8 as8 = *(const s16x8*)&a_lds[m * 392 + c0];
        s16x8 ao8 = *(const s16x8*)&a_lds[m * 392 + 192 + c0];

        float y[8];
#pragma unroll
        for (int j = 0; j < 8; ++j) {
            int c = c0 + j;
            int cin = (T == 4 ? 48 : 0) + (c >> 2);
            float xv = x[(((size_t)b * 96 + cin) * 64 + (2 * h + ((c >> 1) & 1))) * 64
                         + (2 * w + (c & 1))];
            float e = expf(0.4f * bf2f((u16)as8[j]));
            float sj = 2.f - 4.f / (e + 1.f);
            y[j] = xv * expf(sj) + bf2f((u16)ao8[j]);
        }

        if (T == 4) {
            // y2' (bf16, feeds gemm<9>) + y2-half of out (bit-identical to old n_e1+n_o2)
            s16x8 yv;
#pragma unroll
            for (int j = 0; j < 8; ++j) yv[j] = (short)f2bf(y[j]);
            *(s16x8*)&y2out[pix * 192 + c0] = yv;
#pragma unroll
            for (int j = 0; j < 8; ++j) {
                int cg = 192 + c0 + j;
                int o = inv[cg];
                out[(((size_t)b * 384 + o) * 32 + h) * 32 + w] =
                    bf2f((u16)yv[j]) * scale[cg] + offs[cg];
            }
        } else {
            // y1-half of out (bit-identical to old n_o1)
#pragma unroll
            for (int j = 0; j < 8; ++j) {
                int cg = c0 + j;
                int o = inv[cg];
                out[(((size_t)b * 384 + o) * 32 + h) * 32 + w] =
                    y[j] * scale[cg] + offs[cg];
            }
        }
    }
}

extern "C" void kernel_launch(void* const* d_in, const int* in_sizes, int n_in,
                              void* d_out, int out_size, void* d_ws, size_t ws_size,
                              hipStream_t stream)
{
    const float* x        = (const float*)d_in[0];
    const float* w_hi     = (const float*)d_in[1];
    const float* b_hi     = (const float*)d_in[2];
    const float* w_lo     = (const float*)d_in[3];
    const float* b_lo     = (const float*)d_in[4];
    const float* act_norm = (const float*)d_in[5];
    const float* act_off  = (const float*)d_in[6];
    const float* perm_w   = (const float*)d_in[7];
    float* out = (float*)d_out;
    char* ws = (char*)d_ws;

    int*   fwd   = (int*)(ws + WS_FWD);
    int*   inv   = (int*)(ws + WS_INV);
    float* scale = (float*)(ws + WS_SCALE);
    float* offs  = (float*)(ws + WS_OFFS);
    u16*   whi   = (u16*)(ws + WS_WHI);  // packed w_hi bf16 fragments
    u16*   xd    = (u16*)(ws + WS_XD);   // down(x1), persistent
    u16*   wlo   = (u16*)(ws + WS_WLO);  // packed w_lo bf16 fragments
    u16*   y2    = (u16*)(ws + WS_Y2);   // y2'

    k_prep0<<<2, 256, 0, stream>>>(perm_w, act_norm, act_off, fwd, inv, scale, offs);
    k_pack_hi<<<1152, 256, 0, stream>>>(w_hi, whi);
    k_pack_lo<<<2592, 256, 0, stream>>>(w_lo, wlo);
    k_xd<<<24576, 256, 0, stream>>>(x, xd);
    f_gemm<4><<<512, 256, 0, stream>>>(xd, whi, b_hi, x, inv, scale, offs, y2, out);
    f_gemm<9><<<512, 256, 0, stream>>>(y2, wlo, b_lo, x, inv, scale, offs, y2, out);
}